// Round 4
// baseline (331.456 us; speedup 1.0000x reference)
//
#include <hip/hip_runtime.h>
#include <hip/hip_fp16.h>

#define N_NODES  100000
#define N_EDGES  1600000
#define N_GRAPHS 2048
#define VOCAB    1000
#define EMBED    64
#define HID      64
#define N_CL     2
#define CAP      64     // max degree capacity (deg~Poisson(16); P(>=64)~3e-22/node)
#define NBLK     391    // ceil(N_NODES/256)
#define EBLK4    1563   // ceil(N_EDGES/4/256): 4 edges per thread
#define NQUAD    400000 // N_EDGES/4
#define VBLK     63     // ceil(VOCAB*16/256): E-gemm blocks
#define NSWEEP   8
#define RANGE    12500  // N_NODES / NSWEEP
#define PSH      15     // layer-2 gather phase shift: 4 phases x 32768 nodes (~4MB tn2 window/XCD-L2)

typedef __half2 h2;
typedef int i4 __attribute__((ext_vector_type(4)));   // clang ext_vector: valid for nontemporal builtins

// pack float4 -> 4 fp16 (8B)
__device__ inline uint2 pack_h4(float4 a) {
    h2 lo = __float22half2_rn(make_float2(a.x, a.y));
    h2 hi = __float22half2_rn(make_float2(a.z, a.w));
    uint2 r;
    r.x = *reinterpret_cast<unsigned*>(&lo);
    r.y = *reinterpret_cast<unsigned*>(&hi);
    return r;
}

// packed fp16 accumulate: 4x v_pk_add_f16 per 16B row
__device__ inline void acc_h8(h2 acc[4], uint4 raw) {
    acc[0] = __hadd2(acc[0], *reinterpret_cast<h2*>(&raw.x));
    acc[1] = __hadd2(acc[1], *reinterpret_cast<h2*>(&raw.y));
    acc[2] = __hadd2(acc[2], *reinterpret_cast<h2*>(&raw.z));
    acc[3] = __hadd2(acc[3], *reinterpret_cast<h2*>(&raw.w));
}

// convert 4x half2 -> 2x float4
__device__ inline void h8_to_f(const h2 acc[4], float4& A, float4& B) {
    float2 f0 = __half22float2(acc[0]);
    float2 f1 = __half22float2(acc[1]);
    float2 f2 = __half22float2(acc[2]);
    float2 f3 = __half22float2(acc[3]);
    A.x = f0.x; A.y = f0.y; A.z = f1.x; A.w = f1.y;
    B.x = f2.x; B.y = f2.y; B.z = f3.x; B.w = f3.y;
}

__device__ inline void xor_reduce8(float4& A, float4& B) {
#pragma unroll
    for (int m = 8; m <= 32; m <<= 1) {
        A.x += __shfl_xor(A.x, m, 64); A.y += __shfl_xor(A.y, m, 64);
        A.z += __shfl_xor(A.z, m, 64); A.w += __shfl_xor(A.w, m, 64);
        B.x += __shfl_xor(B.x, m, 64); B.y += __shfl_xor(B.y, m, 64);
        B.z += __shfl_xor(B.z, m, 64); B.w += __shfl_xor(B.w, m, 64);
    }
}

// Layer-1 term, reconstructed from hot tables instead of gathering 128B from the 12.8MB tn1 array.
// Bit-exact vs old path: same fp16(dinv*E) rounding (pack_h4 of d*float4), same acc_h8.
// dx[u] = {dinv[u], as_float(x[u])} (800KB, L2-hot); E4 = emb@W1 fp32 (256KB, L2/L1-hot).
__device__ inline void edge_l1(const float2* __restrict__ dx, const float4* __restrict__ E4,
                               int u, int fgl2, h2 acc[4]) {
    float2 t = dx[u];
    float d = t.x;
    int xu = __float_as_int(t.y);
    float4 eA = E4[xu * 16 + fgl2];
    float4 eB = E4[xu * 16 + fgl2 + 1];
    eA.x *= d; eA.y *= d; eA.z *= d; eA.w *= d;
    eB.x *= d; eB.y *= d; eB.z *= d; eB.w *= d;
    uint2 pA = pack_h4(eA);
    uint2 pB = pack_h4(eB);
    uint4 r; r.x = pA.x; r.y = pA.y; r.z = pB.x; r.w = pB.y;
    acc_h8(acc, r);
}

// ================= bucket fill: XCD-aligned target-range sweeps + gb + E=emb@W1 ==================
// (77us floor across 3 MLP variants -> scatter/atomic throughput-bound; left unchanged this round)
__global__ __launch_bounds__(256) void k_fill_slots(const int* __restrict__ row, const int* __restrict__ col,
                                                    int* __restrict__ cnt, int* __restrict__ slots,
                                                    const int* __restrict__ batch, int* __restrict__ start,
                                                    const float* __restrict__ emb, const float* __restrict__ W1,
                                                    float* __restrict__ E) {
    int bid = blockIdx.x;
    if (bid < NSWEEP * EBLK4) {     // ---- fill sweep (XCD-interleaved, 4 edges/thread) ----
        int sweep = bid & (NSWEEP - 1);
        int t = (bid >> 3) * 256 + threadIdx.x;          // quad index
        if (t >= NQUAD) return;
        i4 c4 = __builtin_nontemporal_load((const i4*)col + t);
        unsigned lo = (unsigned)(sweep * RANGE);
        bool m0 = (unsigned)(c4.x - lo) < (unsigned)RANGE;
        bool m1 = (unsigned)(c4.y - lo) < (unsigned)RANGE;
        bool m2 = (unsigned)(c4.z - lo) < (unsigned)RANGE;
        bool m3 = (unsigned)(c4.w - lo) < (unsigned)RANGE;
        if (m0 | m1 | m2 | m3) {
            i4 r4 = __builtin_nontemporal_load((const i4*)row + t);
            if (m0) { int pos = atomicAdd(&cnt[c4.x], 1); if (pos < CAP) slots[c4.x * CAP + pos] = r4.x; }
            if (m1) { int pos = atomicAdd(&cnt[c4.y], 1); if (pos < CAP) slots[c4.y * CAP + pos] = r4.y; }
            if (m2) { int pos = atomicAdd(&cnt[c4.z], 1); if (pos < CAP) slots[c4.z * CAP + pos] = r4.z; }
            if (m3) { int pos = atomicAdd(&cnt[c4.w], 1); if (pos < CAP) slots[c4.w * CAP + pos] = r4.w; }
        }
    } else if (bid < NSWEEP * EBLK4 + NBLK) {  // ---- graph boundaries from sorted batch ----
        int v = (bid - NSWEEP * EBLK4) * 256 + threadIdx.x;
        if (v >= N_NODES) return;
        int b = batch[v];
        int pb = (v == 0) ? -1 : batch[v - 1];
        for (int g = pb + 1; g <= b; ++g) start[g] = v;
        if (v == N_NODES - 1)
            for (int g = b + 1; g <= N_GRAPHS; ++g) start[g] = N_NODES;
    } else {                        // ---- E[j] = emb[j] @ W1 (1000x64, float4/thread) ----
        int t = (bid - NSWEEP * EBLK4 - NBLK) * 256 + threadIdx.x;
        int j = t >> 4;
        int f4 = t & 15;
        if (j >= VOCAB) return;
        const float4* W4 = (const float4*)W1;
        const float* er = emb + j * EMBED;
        float4 acc = make_float4(0.f, 0.f, 0.f, 0.f);
#pragma unroll 8
        for (int k = 0; k < EMBED; ++k) {
            float hv = er[k];
            float4 w = W4[k * 16 + f4];
            acc.x += hv * w.x; acc.y += hv * w.y; acc.z += hv * w.z; acc.w += hv * w.w;
        }
        ((float4*)E)[t] = acc;
    }
}

// ================= dx[v] = { rsqrt(cnt[v]+1), as_float(x[v]) } =================
__global__ __launch_bounds__(256) void k_prep(const int* __restrict__ x, const int* __restrict__ cnt,
                                              float2* __restrict__ dx) {
    int v = blockIdx.x * 256 + threadIdx.x;
    if (v >= N_NODES) return;
    dx[v] = make_float2(rsqrtf((float)(cnt[v] + 1)), __int_as_float(x[v]));
}

// ================= fused: layer-1 aggregate (hot-table reconstruct) + finalize + layer-2 GEMM ====
// 2 nodes/wave; lane = (es[0..7], fg[0..7]); terms rebuilt from dx+E (L2-hot) -> no 12.8MB gather
__global__ __launch_bounds__(256) void k_agg_gemm(const float2* __restrict__ dx,
                                                  const float4* __restrict__ E4,
                                                  const int* __restrict__ cnt,
                                                  const int* __restrict__ slots,
                                                  const float* __restrict__ bias,
                                                  const float* __restrict__ W2,
                                                  __half* __restrict__ tn2) {
    __shared__ float hrow[8][HID];
    int wid = threadIdx.x >> 6;
    int lane = threadIdx.x & 63;
    int fg = lane & 7;
    int fgl2 = fg * 2;
    int es = lane >> 3;
    int v0 = blockIdx.x * 8 + wid * 2;
    int v1 = v0 + 1;
    int c0 = cnt[v0], c1 = cnt[v1];
    int n0 = min(c0, CAP), n1 = min(c1, CAP);
    const int* sl0 = slots + v0 * CAP;
    const int* sl1 = slots + v1 * CAP;
    h2 z = __float2half2_rn(0.f);
    h2 a0[4] = {z, z, z, z};
    h2 a1[4] = {z, z, z, z};
    int base = es * 4, b2 = 32 + es * 4;
    int4 q0 = ((const int4*)sl0)[es];
    int4 q1 = ((const int4*)sl1)[es];
    if (es == 0) edge_l1(dx, E4, v0, fgl2, a0);   // self loop v0
    if (es == 1) edge_l1(dx, E4, v1, fgl2, a1);   // self loop v1
    if (base + 0 < n0) edge_l1(dx, E4, q0.x, fgl2, a0);
    if (base + 0 < n1) edge_l1(dx, E4, q1.x, fgl2, a1);
    if (base + 1 < n0) edge_l1(dx, E4, q0.y, fgl2, a0);
    if (base + 1 < n1) edge_l1(dx, E4, q1.y, fgl2, a1);
    if (base + 2 < n0) edge_l1(dx, E4, q0.z, fgl2, a0);
    if (base + 2 < n1) edge_l1(dx, E4, q1.z, fgl2, a1);
    if (base + 3 < n0) edge_l1(dx, E4, q0.w, fgl2, a0);
    if (base + 3 < n1) edge_l1(dx, E4, q1.w, fgl2, a1);
    if (n0 > 32 || n1 > 32) {               // rare phase (deg ~Poisson(16))
        int4 p0 = ((const int4*)sl0)[8 + es];
        int4 p1 = ((const int4*)sl1)[8 + es];
        if (b2 + 0 < n0) edge_l1(dx, E4, p0.x, fgl2, a0);
        if (b2 + 0 < n1) edge_l1(dx, E4, p1.x, fgl2, a1);
        if (b2 + 1 < n0) edge_l1(dx, E4, p0.y, fgl2, a0);
        if (b2 + 1 < n1) edge_l1(dx, E4, p1.y, fgl2, a1);
        if (b2 + 2 < n0) edge_l1(dx, E4, p0.z, fgl2, a0);
        if (b2 + 2 < n1) edge_l1(dx, E4, p1.z, fgl2, a1);
        if (b2 + 3 < n0) edge_l1(dx, E4, p0.w, fgl2, a0);
        if (b2 + 3 < n1) edge_l1(dx, E4, p1.w, fgl2, a1);
    }
    float4 a0A, a0B, a1A, a1B;
    h8_to_f(a0, a0A, a0B);
    h8_to_f(a1, a1A, a1B);
    xor_reduce8(a0A, a0B);
    xor_reduce8(a1A, a1B);
    float d0 = rsqrtf((float)(c0 + 1));
    float d1 = rsqrtf((float)(c1 + 1));
    float4 bA = ((const float4*)bias)[fg * 2 + 0];
    float4 bB = ((const float4*)bias)[fg * 2 + 1];
    if (es == 0) {
        float4 oA, oB;
        oA.x = fmaxf(d0 * a0A.x + bA.x, 0.f); oA.y = fmaxf(d0 * a0A.y + bA.y, 0.f);
        oA.z = fmaxf(d0 * a0A.z + bA.z, 0.f); oA.w = fmaxf(d0 * a0A.w + bA.w, 0.f);
        oB.x = fmaxf(d0 * a0B.x + bB.x, 0.f); oB.y = fmaxf(d0 * a0B.y + bB.y, 0.f);
        oB.z = fmaxf(d0 * a0B.z + bB.z, 0.f); oB.w = fmaxf(d0 * a0B.w + bB.w, 0.f);
        ((float4*)&hrow[wid * 2][fg * 8])[0] = oA;
        ((float4*)&hrow[wid * 2][fg * 8])[1] = oB;
    }
    if (es == 1) {
        float4 oA, oB;
        oA.x = fmaxf(d1 * a1A.x + bA.x, 0.f); oA.y = fmaxf(d1 * a1A.y + bA.y, 0.f);
        oA.z = fmaxf(d1 * a1A.z + bA.z, 0.f); oA.w = fmaxf(d1 * a1A.w + bA.w, 0.f);
        oB.x = fmaxf(d1 * a1B.x + bB.x, 0.f); oB.y = fmaxf(d1 * a1B.y + bB.y, 0.f);
        oB.z = fmaxf(d1 * a1B.z + bB.z, 0.f); oB.w = fmaxf(d1 * a1B.w + bB.w, 0.f);
        ((float4*)&hrow[wid * 2 + 1][fg * 8])[0] = oA;
        ((float4*)&hrow[wid * 2 + 1][fg * 8])[1] = oB;
    }
    __syncthreads();
    // ---- layer-2 GEMM: lane computes feature `lane` for both nodes (float4 LDS broadcast reads) ----
    const float4* h04 = (const float4*)hrow[wid * 2];
    const float4* h14 = (const float4*)hrow[wid * 2 + 1];
    float s0 = 0.f, s1 = 0.f;
#pragma unroll 4
    for (int k4 = 0; k4 < 16; ++k4) {
        float4 ha = h04[k4];
        float4 hb = h14[k4];
        int k = k4 * 4;
        float w0 = W2[(k + 0) * HID + lane];
        float w1 = W2[(k + 1) * HID + lane];
        float w2 = W2[(k + 2) * HID + lane];
        float w3 = W2[(k + 3) * HID + lane];
        s0 += ha.x * w0 + ha.y * w1 + ha.z * w2 + ha.w * w3;
        s1 += hb.x * w0 + hb.y * w1 + hb.z * w2 + hb.w * w3;
    }
    tn2[v0 * HID + lane] = __float2half(d0 * s0);
    tn2[v1 * HID + lane] = __float2half(d1 * s1);
}

// ---------------- layer-2 aggregate: phased gather (4 x 32768-node source windows) ----------------
// Slot indices live in registers; each phase only gathers sources in a ~4MB tn2 window so
// concurrently-running blocks (round-robin over XCDs) share an L2-resident window.
__global__ __launch_bounds__(256) void k_agg(const uint4* __restrict__ tn,
                                             const int* __restrict__ cnt,
                                             const int* __restrict__ slots,
                                             const float* __restrict__ bias,
                                             float* __restrict__ h) {
    int wid = threadIdx.x >> 6;
    int lane = threadIdx.x & 63;
    int fg = lane & 7;
    int es = lane >> 3;
    int v0 = blockIdx.x * 8 + wid * 2;
    int v1 = v0 + 1;
    int c0 = cnt[v0], c1 = cnt[v1];
    int n0 = min(c0, CAP), n1 = min(c1, CAP);
    const int* sl0 = slots + v0 * CAP;
    const int* sl1 = slots + v1 * CAP;
    h2 z = __float2half2_rn(0.f);
    h2 a0[4] = {z, z, z, z};
    h2 a1[4] = {z, z, z, z};
    if (es == 0) acc_h8(a0, tn[v0 * 8 + fg]);
    if (es == 1) acc_h8(a1, tn[v1 * 8 + fg]);
    int base = es * 4, b2 = 32 + es * 4;
    int4 q0 = ((const int4*)sl0)[es];
    int4 q1 = ((const int4*)sl1)[es];
    int4 p0 = ((const int4*)sl0)[8 + es];
    int4 p1 = ((const int4*)sl1)[8 + es];
    // phase tags: -1 = invalid slot, else source-range id (u >> PSH, 0..3)
    int t0x = (base + 0 < n0) ? (q0.x >> PSH) : -1;
    int t1x = (base + 0 < n1) ? (q1.x >> PSH) : -1;
    int t0y = (base + 1 < n0) ? (q0.y >> PSH) : -1;
    int t1y = (base + 1 < n1) ? (q1.y >> PSH) : -1;
    int t0z = (base + 2 < n0) ? (q0.z >> PSH) : -1;
    int t1z = (base + 2 < n1) ? (q1.z >> PSH) : -1;
    int t0w = (base + 3 < n0) ? (q0.w >> PSH) : -1;
    int t1w = (base + 3 < n1) ? (q1.w >> PSH) : -1;
    int u0x = (b2 + 0 < n0) ? (p0.x >> PSH) : -1;
    int u1x = (b2 + 0 < n1) ? (p1.x >> PSH) : -1;
    int u0y = (b2 + 1 < n0) ? (p0.y >> PSH) : -1;
    int u1y = (b2 + 1 < n1) ? (p1.y >> PSH) : -1;
    int u0z = (b2 + 2 < n0) ? (p0.z >> PSH) : -1;
    int u1z = (b2 + 2 < n1) ? (p1.z >> PSH) : -1;
    int u0w = (b2 + 3 < n0) ? (p0.w >> PSH) : -1;
    int u1w = (b2 + 3 < n1) ? (p1.w >> PSH) : -1;
#pragma unroll 1
    for (int p = 0; p < 4; ++p) {
        if (t0x == p) acc_h8(a0, tn[q0.x * 8 + fg]);
        if (t1x == p) acc_h8(a1, tn[q1.x * 8 + fg]);
        if (t0y == p) acc_h8(a0, tn[q0.y * 8 + fg]);
        if (t1y == p) acc_h8(a1, tn[q1.y * 8 + fg]);
        if (t0z == p) acc_h8(a0, tn[q0.z * 8 + fg]);
        if (t1z == p) acc_h8(a1, tn[q1.z * 8 + fg]);
        if (t0w == p) acc_h8(a0, tn[q0.w * 8 + fg]);
        if (t1w == p) acc_h8(a1, tn[q1.w * 8 + fg]);
        if (u0x == p) acc_h8(a0, tn[p0.x * 8 + fg]);
        if (u1x == p) acc_h8(a1, tn[p1.x * 8 + fg]);
        if (u0y == p) acc_h8(a0, tn[p0.y * 8 + fg]);
        if (u1y == p) acc_h8(a1, tn[p1.y * 8 + fg]);
        if (u0z == p) acc_h8(a0, tn[p0.z * 8 + fg]);
        if (u1z == p) acc_h8(a1, tn[p1.z * 8 + fg]);
        if (u0w == p) acc_h8(a0, tn[p0.w * 8 + fg]);
        if (u1w == p) acc_h8(a1, tn[p1.w * 8 + fg]);
    }
    float4 a0A, a0B, a1A, a1B;
    h8_to_f(a0, a0A, a0B);
    h8_to_f(a1, a1A, a1B);
    xor_reduce8(a0A, a0B);
    xor_reduce8(a1A, a1B);
    float4 bA = ((const float4*)bias)[fg * 2 + 0];
    float4 bB = ((const float4*)bias)[fg * 2 + 1];
    if (es == 0) {
        float d0 = rsqrtf((float)(c0 + 1));
        float4 oA, oB;
        oA.x = fmaxf(d0 * a0A.x + bA.x, 0.f); oA.y = fmaxf(d0 * a0A.y + bA.y, 0.f);
        oA.z = fmaxf(d0 * a0A.z + bA.z, 0.f); oA.w = fmaxf(d0 * a0A.w + bA.w, 0.f);
        oB.x = fmaxf(d0 * a0B.x + bB.x, 0.f); oB.y = fmaxf(d0 * a0B.y + bB.y, 0.f);
        oB.z = fmaxf(d0 * a0B.z + bB.z, 0.f); oB.w = fmaxf(d0 * a0B.w + bB.w, 0.f);
        ((float4*)&h[v0 * HID + fg * 8])[0] = oA;
        ((float4*)&h[v0 * HID + fg * 8])[1] = oB;
    }
    if (es == 1) {
        float d1 = rsqrtf((float)(c1 + 1));
        float4 oA, oB;
        oA.x = fmaxf(d1 * a1A.x + bA.x, 0.f); oA.y = fmaxf(d1 * a1A.y + bA.y, 0.f);
        oA.z = fmaxf(d1 * a1A.z + bA.z, 0.f); oA.w = fmaxf(d1 * a1A.w + bA.w, 0.f);
        oB.x = fmaxf(d1 * a1B.x + bB.x, 0.f); oB.y = fmaxf(d1 * a1B.y + bB.y, 0.f);
        oB.z = fmaxf(d1 * a1B.z + bB.z, 0.f); oB.w = fmaxf(d1 * a1B.w + bB.w, 0.f);
        ((float4*)&h[v1 * HID + fg * 8])[0] = oA;
        ((float4*)&h[v1 * HID + fg * 8])[1] = oB;
    }
}

// ---------------- fused mean-pool + projection ----------------
__global__ __launch_bounds__(256) void k_pool_out(const float* __restrict__ h,
                                                  const int* __restrict__ start,
                                                  const float* __restrict__ Wl,
                                                  const float* __restrict__ bl,
                                                  float* __restrict__ out) {
    int g = (blockIdx.x * 256 + threadIdx.x) >> 6;
    int f = threadIdx.x & 63;
    if (g >= N_GRAPHS) return;
    int s = start[g], e = start[g + 1];
    float acc = 0.f;
    int v = s;
    for (; v + 4 <= e; v += 4) {
        float a0 = h[(v + 0) * HID + f];
        float a1 = h[(v + 1) * HID + f];
        float a2 = h[(v + 2) * HID + f];
        float a3 = h[(v + 3) * HID + f];
        acc += (a0 + a1) + (a2 + a3);
    }
    for (; v < e; ++v) acc += h[v * HID + f];
    float m = acc / fmaxf((float)(e - s), 1.f);
    float p0 = m * Wl[f * N_CL + 0];
    float p1 = m * Wl[f * N_CL + 1];
#pragma unroll
    for (int off = 32; off > 0; off >>= 1) {
        p0 += __shfl_down(p0, off, 64);
        p1 += __shfl_down(p1, off, 64);
    }
    if (f == 0) {
        out[g * N_CL + 0] = p0 + bl[0];
        out[g * N_CL + 1] = p1 + bl[1];
    }
}

extern "C" void kernel_launch(void* const* d_in, const int* in_sizes, int n_in,
                              void* d_out, int out_size, void* d_ws, size_t ws_size,
                              hipStream_t stream) {
    const int*   x     = (const int*)d_in[0];
    const int*   ei    = (const int*)d_in[1];        // [2, E] flat: sources then targets
    const int*   batch = (const int*)d_in[2];
    const float* emb   = (const float*)d_in[3];
    const float* W1    = (const float*)d_in[4];
    const float* b1    = (const float*)d_in[5];
    const float* W2    = (const float*)d_in[6];
    const float* b2    = (const float*)d_in[7];
    const float* Wl    = (const float*)d_in[8];
    const float* bl    = (const float*)d_in[9];
    float* out = (float*)d_out;

    const int* row = ei;             // sources
    const int* col = ei + N_EDGES;   // targets

    // ---- workspace layout (~66 MB) ----
    char* ws = (char*)d_ws;
    size_t off = 0;
    auto alloc = [&](size_t bytes) { char* p = ws + off; off = (off + bytes + 511) & ~(size_t)511; return p; };
    const size_t FEAT_BYTES  = (size_t)N_NODES * HID * sizeof(float);      // 25.6 MB
    const size_t FEATH_BYTES = (size_t)N_NODES * HID * sizeof(__half);     // 12.8 MB
    float* A      = (float*)alloc(FEAT_BYTES);             // h2 fp32 (layer-2 output)
    __half* Bt    = (__half*)alloc(FEATH_BYTES);           // tn2 fp16
    int*   slots  = (int*)  alloc((size_t)N_NODES * CAP * sizeof(int));    // 25.6 MB
    float* E      = (float*)alloc((size_t)VOCAB * HID * sizeof(float));    // 256 KB
    int*   start  = (int*)  alloc((size_t)(N_GRAPHS + 1) * sizeof(int));
    int*   cnt    = (int*)  alloc((size_t)N_NODES * sizeof(int));          // zeroed
    float2* dx    = (float2*)alloc((size_t)N_NODES * sizeof(float2));      // 800 KB hot table

    dim3 blk(256);
    dim3 g_fill(NSWEEP * EBLK4 + NBLK + VBLK);    // fill sweeps (4 edges/thread) | gb | E-gemm
    dim3 g_prep(NBLK);
    dim3 g_agg(N_NODES / 8);                      // 12500 exact (8 nodes/block, 2/wave)
    dim3 g_po((N_GRAPHS * 64 + 255) / 256);       // 512

    hipMemsetAsync(cnt, 0, (size_t)N_NODES * sizeof(int), stream);

    // ---- single scattered pass, XCD-aligned range sweeps ----
    k_fill_slots<<<g_fill, blk, 0, stream>>>(row, col, cnt, slots, batch, start, emb, W1, E);

    // ---- dx = {dinv, x} hot table ----
    k_prep<<<g_prep, blk, 0, stream>>>(x, cnt, dx);

    // ---- layer-1 aggregate (hot-table reconstruct) + layer-2 GEMM (tn2 -> fp16) ----
    k_agg_gemm<<<g_agg, blk, 0, stream>>>(dx, (const float4*)E, cnt, slots, b1, W2, Bt);

    // ---- layer-2 aggregate (phased gather) -> h2 fp32 (A) ----
    k_agg<<<g_agg, blk, 0, stream>>>((const uint4*)Bt, cnt, slots, b2, A);

    // ---- fused pool + classify ----
    k_pool_out<<<g_po, blk, 0, stream>>>(A, start, Wl, bl, out);
}

// Round 5
// 289.648 us; speedup vs baseline: 1.1443x; 1.1443x over previous
//
#include <hip/hip_runtime.h>
#include <hip/hip_fp16.h>

#define N_NODES  100000
#define N_EDGES  1600000
#define N_GRAPHS 2048
#define VOCAB    1000
#define EMBED    64
#define HID      64
#define N_CL     2
#define CAP      64     // max degree capacity (deg~Poisson(16); P(>=64)~3e-22/node)
#define NBLK     391    // ceil(N_NODES/256)
#define EBLK4    1563   // ceil(N_EDGES/4/256): 4 edges per thread
#define NQUAD    400000 // N_EDGES/4
#define VBLK     63     // ceil(VOCAB*16/256): E-gemm blocks
#define NSWEEP   8
#define RANGE    12500  // N_NODES / NSWEEP

typedef __half2 h2;
typedef int i4 __attribute__((ext_vector_type(4)));   // clang ext_vector: valid for nontemporal builtins

// packed fp16 accumulate: 4x v_pk_add_f16 per 16B row
__device__ inline void acc_h8(h2 acc[4], uint4 raw) {
    acc[0] = __hadd2(acc[0], *reinterpret_cast<h2*>(&raw.x));
    acc[1] = __hadd2(acc[1], *reinterpret_cast<h2*>(&raw.y));
    acc[2] = __hadd2(acc[2], *reinterpret_cast<h2*>(&raw.z));
    acc[3] = __hadd2(acc[3], *reinterpret_cast<h2*>(&raw.w));
}

// convert 4x half2 -> 2x float4
__device__ inline void h8_to_f(const h2 acc[4], float4& A, float4& B) {
    float2 f0 = __half22float2(acc[0]);
    float2 f1 = __half22float2(acc[1]);
    float2 f2 = __half22float2(acc[2]);
    float2 f3 = __half22float2(acc[3]);
    A.x = f0.x; A.y = f0.y; A.z = f1.x; A.w = f1.y;
    B.x = f2.x; B.y = f2.y; B.z = f3.x; B.w = f3.y;
}

__device__ inline void xor_reduce8(float4& A, float4& B) {
#pragma unroll
    for (int m = 8; m <= 32; m <<= 1) {
        A.x += __shfl_xor(A.x, m, 64); A.y += __shfl_xor(A.y, m, 64);
        A.z += __shfl_xor(A.z, m, 64); A.w += __shfl_xor(A.w, m, 64);
        B.x += __shfl_xor(B.x, m, 64); B.y += __shfl_xor(B.y, m, 64);
        B.z += __shfl_xor(B.z, m, 64); B.w += __shfl_xor(B.w, m, 64);
    }
}

// Layer-1 term in pure fp32 FMA: 8 v_fma + one 8B hot gather + two L2-hot float4 loads per edge.
// (Round-4's fp16 pack path proved the traffic win — FETCH 85.7->11.3MB — but cost 16 VALU/edge;
//  this halves the VALU work and improves accuracy vs the fp16-accumulate path.)
// dx[u] = {dinv[u], as_float(x[u])} (800KB, L2-hot); E4 = emb@W1 fp32 (256KB, L2-hot).
__device__ inline void edge_l1f(const float2* __restrict__ dx, const float4* __restrict__ E4,
                                int u, int fgl2, float4& A, float4& B) {
    float2 t = dx[u];
    float d = t.x;
    int xu = __float_as_int(t.y);
    float4 eA = E4[xu * 16 + fgl2];
    float4 eB = E4[xu * 16 + fgl2 + 1];
    A.x += d * eA.x; A.y += d * eA.y; A.z += d * eA.z; A.w += d * eA.w;
    B.x += d * eB.x; B.y += d * eB.y; B.z += d * eB.z; B.w += d * eB.w;
}

// MLP-maximized fp16 gather (layer 2): int4 slot-index loads, v0/v1 interleaved,
// up to 8 outstanding 128B gathers. Round-3-proven.
__device__ inline void gather2(const uint4* __restrict__ tn,
                               const int* __restrict__ sl0, const int* __restrict__ sl1,
                               int n0, int n1, int es, int fg, h2 a0[4], h2 a1[4]) {
    int base = es * 4;
    int4 q0 = ((const int4*)sl0)[es];       // slots base..base+3 of v0 (safe: full CAP allocated)
    int4 q1 = ((const int4*)sl1)[es];
    if (base + 0 < n0) acc_h8(a0, tn[q0.x * 8 + fg]);
    if (base + 0 < n1) acc_h8(a1, tn[q1.x * 8 + fg]);
    if (base + 1 < n0) acc_h8(a0, tn[q0.y * 8 + fg]);
    if (base + 1 < n1) acc_h8(a1, tn[q1.y * 8 + fg]);
    if (base + 2 < n0) acc_h8(a0, tn[q0.z * 8 + fg]);
    if (base + 2 < n1) acc_h8(a1, tn[q1.z * 8 + fg]);
    if (base + 3 < n0) acc_h8(a0, tn[q0.w * 8 + fg]);
    if (base + 3 < n1) acc_h8(a1, tn[q1.w * 8 + fg]);
    if (n0 > 32 || n1 > 32) {               // rare phase (deg ~Poisson(16))
        int b2 = 32 + es * 4;
        int4 p0 = ((const int4*)sl0)[8 + es];
        int4 p1 = ((const int4*)sl1)[8 + es];
        if (b2 + 0 < n0) acc_h8(a0, tn[p0.x * 8 + fg]);
        if (b2 + 0 < n1) acc_h8(a1, tn[p1.x * 8 + fg]);
        if (b2 + 1 < n0) acc_h8(a0, tn[p0.y * 8 + fg]);
        if (b2 + 1 < n1) acc_h8(a1, tn[p1.y * 8 + fg]);
        if (b2 + 2 < n0) acc_h8(a0, tn[p0.z * 8 + fg]);
        if (b2 + 2 < n1) acc_h8(a1, tn[p1.z * 8 + fg]);
        if (b2 + 3 < n0) acc_h8(a0, tn[p0.w * 8 + fg]);
        if (b2 + 3 < n1) acc_h8(a1, tn[p1.w * 8 + fg]);
    }
}

// ================= bucket fill: XCD-aligned target-range sweeps + gb + E=emb@W1 ==================
// (77us floor across 3 MLP variants -> scatter/atomic throughput-bound; left unchanged)
__global__ __launch_bounds__(256) void k_fill_slots(const int* __restrict__ row, const int* __restrict__ col,
                                                    int* __restrict__ cnt, int* __restrict__ slots,
                                                    const int* __restrict__ batch, int* __restrict__ start,
                                                    const float* __restrict__ emb, const float* __restrict__ W1,
                                                    float* __restrict__ E) {
    int bid = blockIdx.x;
    if (bid < NSWEEP * EBLK4) {     // ---- fill sweep (XCD-interleaved, 4 edges/thread) ----
        int sweep = bid & (NSWEEP - 1);
        int t = (bid >> 3) * 256 + threadIdx.x;          // quad index
        if (t >= NQUAD) return;
        i4 c4 = __builtin_nontemporal_load((const i4*)col + t);
        unsigned lo = (unsigned)(sweep * RANGE);
        bool m0 = (unsigned)(c4.x - lo) < (unsigned)RANGE;
        bool m1 = (unsigned)(c4.y - lo) < (unsigned)RANGE;
        bool m2 = (unsigned)(c4.z - lo) < (unsigned)RANGE;
        bool m3 = (unsigned)(c4.w - lo) < (unsigned)RANGE;
        if (m0 | m1 | m2 | m3) {
            i4 r4 = __builtin_nontemporal_load((const i4*)row + t);
            if (m0) { int pos = atomicAdd(&cnt[c4.x], 1); if (pos < CAP) slots[c4.x * CAP + pos] = r4.x; }
            if (m1) { int pos = atomicAdd(&cnt[c4.y], 1); if (pos < CAP) slots[c4.y * CAP + pos] = r4.y; }
            if (m2) { int pos = atomicAdd(&cnt[c4.z], 1); if (pos < CAP) slots[c4.z * CAP + pos] = r4.z; }
            if (m3) { int pos = atomicAdd(&cnt[c4.w], 1); if (pos < CAP) slots[c4.w * CAP + pos] = r4.w; }
        }
    } else if (bid < NSWEEP * EBLK4 + NBLK) {  // ---- graph boundaries from sorted batch ----
        int v = (bid - NSWEEP * EBLK4) * 256 + threadIdx.x;
        if (v >= N_NODES) return;
        int b = batch[v];
        int pb = (v == 0) ? -1 : batch[v - 1];
        for (int g = pb + 1; g <= b; ++g) start[g] = v;
        if (v == N_NODES - 1)
            for (int g = b + 1; g <= N_GRAPHS; ++g) start[g] = N_NODES;
    } else {                        // ---- E[j] = emb[j] @ W1 (1000x64, float4/thread) ----
        int t = (bid - NSWEEP * EBLK4 - NBLK) * 256 + threadIdx.x;
        int j = t >> 4;
        int f4 = t & 15;
        if (j >= VOCAB) return;
        const float4* W4 = (const float4*)W1;
        const float* er = emb + j * EMBED;
        float4 acc = make_float4(0.f, 0.f, 0.f, 0.f);
#pragma unroll 8
        for (int k = 0; k < EMBED; ++k) {
            float hv = er[k];
            float4 w = W4[k * 16 + f4];
            acc.x += hv * w.x; acc.y += hv * w.y; acc.z += hv * w.z; acc.w += hv * w.w;
        }
        ((float4*)E)[t] = acc;
    }
}

// ================= dx[v] = { rsqrt(cnt[v]+1), as_float(x[v]) } =================
__global__ __launch_bounds__(256) void k_prep(const int* __restrict__ x, const int* __restrict__ cnt,
                                              float2* __restrict__ dx) {
    int v = blockIdx.x * 256 + threadIdx.x;
    if (v >= N_NODES) return;
    dx[v] = make_float2(rsqrtf((float)(cnt[v] + 1)), __int_as_float(x[v]));
}

// ================= fused: layer-1 aggregate (fp32 FMA reconstruct) + finalize + layer-2 GEMM ====
// 2 nodes/wave; lane = (es[0..7], fg[0..7]); terms rebuilt from dx+E (L2-hot) -> no 12.8MB gather
__global__ __launch_bounds__(256) void k_agg_gemm(const float2* __restrict__ dx,
                                                  const float4* __restrict__ E4,
                                                  const int* __restrict__ cnt,
                                                  const int* __restrict__ slots,
                                                  const float* __restrict__ bias,
                                                  const float* __restrict__ W2,
                                                  __half* __restrict__ tn2) {
    __shared__ float hrow[8][HID];
    int wid = threadIdx.x >> 6;
    int lane = threadIdx.x & 63;
    int fg = lane & 7;
    int fgl2 = fg * 2;
    int es = lane >> 3;
    int v0 = blockIdx.x * 8 + wid * 2;
    int v1 = v0 + 1;
    int c0 = cnt[v0], c1 = cnt[v1];
    int n0 = min(c0, CAP), n1 = min(c1, CAP);
    const int* sl0 = slots + v0 * CAP;
    const int* sl1 = slots + v1 * CAP;
    float4 a0A = make_float4(0.f, 0.f, 0.f, 0.f), a0B = a0A;
    float4 a1A = a0A, a1B = a0A;
    int base = es * 4, b2 = 32 + es * 4;
    int4 q0 = ((const int4*)sl0)[es];
    int4 q1 = ((const int4*)sl1)[es];
    if (es == 0) edge_l1f(dx, E4, v0, fgl2, a0A, a0B);   // self loop v0
    if (es == 1) edge_l1f(dx, E4, v1, fgl2, a1A, a1B);   // self loop v1
    if (base + 0 < n0) edge_l1f(dx, E4, q0.x, fgl2, a0A, a0B);
    if (base + 0 < n1) edge_l1f(dx, E4, q1.x, fgl2, a1A, a1B);
    if (base + 1 < n0) edge_l1f(dx, E4, q0.y, fgl2, a0A, a0B);
    if (base + 1 < n1) edge_l1f(dx, E4, q1.y, fgl2, a1A, a1B);
    if (base + 2 < n0) edge_l1f(dx, E4, q0.z, fgl2, a0A, a0B);
    if (base + 2 < n1) edge_l1f(dx, E4, q1.z, fgl2, a1A, a1B);
    if (base + 3 < n0) edge_l1f(dx, E4, q0.w, fgl2, a0A, a0B);
    if (base + 3 < n1) edge_l1f(dx, E4, q1.w, fgl2, a1A, a1B);
    if (n0 > 32 || n1 > 32) {               // rare phase (deg ~Poisson(16))
        int4 p0 = ((const int4*)sl0)[8 + es];
        int4 p1 = ((const int4*)sl1)[8 + es];
        if (b2 + 0 < n0) edge_l1f(dx, E4, p0.x, fgl2, a0A, a0B);
        if (b2 + 0 < n1) edge_l1f(dx, E4, p1.x, fgl2, a1A, a1B);
        if (b2 + 1 < n0) edge_l1f(dx, E4, p0.y, fgl2, a0A, a0B);
        if (b2 + 1 < n1) edge_l1f(dx, E4, p1.y, fgl2, a1A, a1B);
        if (b2 + 2 < n0) edge_l1f(dx, E4, p0.z, fgl2, a0A, a0B);
        if (b2 + 2 < n1) edge_l1f(dx, E4, p1.z, fgl2, a1A, a1B);
        if (b2 + 3 < n0) edge_l1f(dx, E4, p0.w, fgl2, a0A, a0B);
        if (b2 + 3 < n1) edge_l1f(dx, E4, p1.w, fgl2, a1A, a1B);
    }
    xor_reduce8(a0A, a0B);
    xor_reduce8(a1A, a1B);
    float d0 = rsqrtf((float)(c0 + 1));
    float d1 = rsqrtf((float)(c1 + 1));
    float4 bA = ((const float4*)bias)[fg * 2 + 0];
    float4 bB = ((const float4*)bias)[fg * 2 + 1];
    if (es == 0) {
        float4 oA, oB;
        oA.x = fmaxf(d0 * a0A.x + bA.x, 0.f); oA.y = fmaxf(d0 * a0A.y + bA.y, 0.f);
        oA.z = fmaxf(d0 * a0A.z + bA.z, 0.f); oA.w = fmaxf(d0 * a0A.w + bA.w, 0.f);
        oB.x = fmaxf(d0 * a0B.x + bB.x, 0.f); oB.y = fmaxf(d0 * a0B.y + bB.y, 0.f);
        oB.z = fmaxf(d0 * a0B.z + bB.z, 0.f); oB.w = fmaxf(d0 * a0B.w + bB.w, 0.f);
        ((float4*)&hrow[wid * 2][fg * 8])[0] = oA;
        ((float4*)&hrow[wid * 2][fg * 8])[1] = oB;
    }
    if (es == 1) {
        float4 oA, oB;
        oA.x = fmaxf(d1 * a1A.x + bA.x, 0.f); oA.y = fmaxf(d1 * a1A.y + bA.y, 0.f);
        oA.z = fmaxf(d1 * a1A.z + bA.z, 0.f); oA.w = fmaxf(d1 * a1A.w + bA.w, 0.f);
        oB.x = fmaxf(d1 * a1B.x + bB.x, 0.f); oB.y = fmaxf(d1 * a1B.y + bB.y, 0.f);
        oB.z = fmaxf(d1 * a1B.z + bB.z, 0.f); oB.w = fmaxf(d1 * a1B.w + bB.w, 0.f);
        ((float4*)&hrow[wid * 2 + 1][fg * 8])[0] = oA;
        ((float4*)&hrow[wid * 2 + 1][fg * 8])[1] = oB;
    }
    __syncthreads();
    // ---- layer-2 GEMM: lane computes feature `lane` for both nodes (float4 LDS broadcast reads) ----
    const float4* h04 = (const float4*)hrow[wid * 2];
    const float4* h14 = (const float4*)hrow[wid * 2 + 1];
    float s0 = 0.f, s1 = 0.f;
#pragma unroll 4
    for (int k4 = 0; k4 < 16; ++k4) {
        float4 ha = h04[k4];
        float4 hb = h14[k4];
        int k = k4 * 4;
        float w0 = W2[(k + 0) * HID + lane];
        float w1 = W2[(k + 1) * HID + lane];
        float w2 = W2[(k + 2) * HID + lane];
        float w3 = W2[(k + 3) * HID + lane];
        s0 += ha.x * w0 + ha.y * w1 + ha.z * w2 + ha.w * w3;
        s1 += hb.x * w0 + hb.y * w1 + hb.z * w2 + hb.w * w3;
    }
    tn2[v0 * HID + lane] = __float2half(d0 * s0);
    tn2[v1 * HID + lane] = __float2half(d1 * s1);
}

// ---------------- layer-2 aggregate (fp16 pk-add, round-3 gather2) — 2 nodes/wave -> fp32 -------
__global__ __launch_bounds__(256) void k_agg(const uint4* __restrict__ tn,
                                             const int* __restrict__ cnt,
                                             const int* __restrict__ slots,
                                             const float* __restrict__ bias,
                                             float* __restrict__ h) {
    int wid = threadIdx.x >> 6;
    int lane = threadIdx.x & 63;
    int fg = lane & 7;
    int es = lane >> 3;
    int v0 = blockIdx.x * 8 + wid * 2;
    int v1 = v0 + 1;
    int c0 = cnt[v0], c1 = cnt[v1];
    int n0 = min(c0, CAP), n1 = min(c1, CAP);
    h2 z = __float2half2_rn(0.f);
    h2 a0[4] = {z, z, z, z};
    h2 a1[4] = {z, z, z, z};
    if (es == 0) acc_h8(a0, tn[v0 * 8 + fg]);
    if (es == 1) acc_h8(a1, tn[v1 * 8 + fg]);
    gather2(tn, slots + v0 * CAP, slots + v1 * CAP, n0, n1, es, fg, a0, a1);
    float4 a0A, a0B, a1A, a1B;
    h8_to_f(a0, a0A, a0B);
    h8_to_f(a1, a1A, a1B);
    xor_reduce8(a0A, a0B);
    xor_reduce8(a1A, a1B);
    float4 bA = ((const float4*)bias)[fg * 2 + 0];
    float4 bB = ((const float4*)bias)[fg * 2 + 1];
    if (es == 0) {
        float d0 = rsqrtf((float)(c0 + 1));
        float4 oA, oB;
        oA.x = fmaxf(d0 * a0A.x + bA.x, 0.f); oA.y = fmaxf(d0 * a0A.y + bA.y, 0.f);
        oA.z = fmaxf(d0 * a0A.z + bA.z, 0.f); oA.w = fmaxf(d0 * a0A.w + bA.w, 0.f);
        oB.x = fmaxf(d0 * a0B.x + bB.x, 0.f); oB.y = fmaxf(d0 * a0B.y + bB.y, 0.f);
        oB.z = fmaxf(d0 * a0B.z + bB.z, 0.f); oB.w = fmaxf(d0 * a0B.w + bB.w, 0.f);
        ((float4*)&h[v0 * HID + fg * 8])[0] = oA;
        ((float4*)&h[v0 * HID + fg * 8])[1] = oB;
    }
    if (es == 1) {
        float d1 = rsqrtf((float)(c1 + 1));
        float4 oA, oB;
        oA.x = fmaxf(d1 * a1A.x + bA.x, 0.f); oA.y = fmaxf(d1 * a1A.y + bA.y, 0.f);
        oA.z = fmaxf(d1 * a1A.z + bA.z, 0.f); oA.w = fmaxf(d1 * a1A.w + bA.w, 0.f);
        oB.x = fmaxf(d1 * a1B.x + bB.x, 0.f); oB.y = fmaxf(d1 * a1B.y + bB.y, 0.f);
        oB.z = fmaxf(d1 * a1B.z + bB.z, 0.f); oB.w = fmaxf(d1 * a1B.w + bB.w, 0.f);
        ((float4*)&h[v1 * HID + fg * 8])[0] = oA;
        ((float4*)&h[v1 * HID + fg * 8])[1] = oB;
    }
}

// ---------------- fused mean-pool + projection ----------------
__global__ __launch_bounds__(256) void k_pool_out(const float* __restrict__ h,
                                                  const int* __restrict__ start,
                                                  const float* __restrict__ Wl,
                                                  const float* __restrict__ bl,
                                                  float* __restrict__ out) {
    int g = (blockIdx.x * 256 + threadIdx.x) >> 6;
    int f = threadIdx.x & 63;
    if (g >= N_GRAPHS) return;
    int s = start[g], e = start[g + 1];
    float acc = 0.f;
    int v = s;
    for (; v + 4 <= e; v += 4) {
        float a0 = h[(v + 0) * HID + f];
        float a1 = h[(v + 1) * HID + f];
        float a2 = h[(v + 2) * HID + f];
        float a3 = h[(v + 3) * HID + f];
        acc += (a0 + a1) + (a2 + a3);
    }
    for (; v < e; ++v) acc += h[v * HID + f];
    float m = acc / fmaxf((float)(e - s), 1.f);
    float p0 = m * Wl[f * N_CL + 0];
    float p1 = m * Wl[f * N_CL + 1];
#pragma unroll
    for (int off = 32; off > 0; off >>= 1) {
        p0 += __shfl_down(p0, off, 64);
        p1 += __shfl_down(p1, off, 64);
    }
    if (f == 0) {
        out[g * N_CL + 0] = p0 + bl[0];
        out[g * N_CL + 1] = p1 + bl[1];
    }
}

extern "C" void kernel_launch(void* const* d_in, const int* in_sizes, int n_in,
                              void* d_out, int out_size, void* d_ws, size_t ws_size,
                              hipStream_t stream) {
    const int*   x     = (const int*)d_in[0];
    const int*   ei    = (const int*)d_in[1];        // [2, E] flat: sources then targets
    const int*   batch = (const int*)d_in[2];
    const float* emb   = (const float*)d_in[3];
    const float* W1    = (const float*)d_in[4];
    const float* b1    = (const float*)d_in[5];
    const float* W2    = (const float*)d_in[6];
    const float* b2    = (const float*)d_in[7];
    const float* Wl    = (const float*)d_in[8];
    const float* bl    = (const float*)d_in[9];
    float* out = (float*)d_out;

    const int* row = ei;             // sources
    const int* col = ei + N_EDGES;   // targets

    // ---- workspace layout (~66 MB) ----
    char* ws = (char*)d_ws;
    size_t off = 0;
    auto alloc = [&](size_t bytes) { char* p = ws + off; off = (off + bytes + 511) & ~(size_t)511; return p; };
    const size_t FEAT_BYTES  = (size_t)N_NODES * HID * sizeof(float);      // 25.6 MB
    const size_t FEATH_BYTES = (size_t)N_NODES * HID * sizeof(__half);     // 12.8 MB
    float* A      = (float*)alloc(FEAT_BYTES);             // h2 fp32 (layer-2 output)
    __half* Bt    = (__half*)alloc(FEATH_BYTES);           // tn2 fp16
    int*   slots  = (int*)  alloc((size_t)N_NODES * CAP * sizeof(int));    // 25.6 MB
    float* E      = (float*)alloc((size_t)VOCAB * HID * sizeof(float));    // 256 KB
    int*   start  = (int*)  alloc((size_t)(N_GRAPHS + 1) * sizeof(int));
    int*   cnt    = (int*)  alloc((size_t)N_NODES * sizeof(int));          // zeroed
    float2* dx    = (float2*)alloc((size_t)N_NODES * sizeof(float2));      // 800 KB hot table

    dim3 blk(256);
    dim3 g_fill(NSWEEP * EBLK4 + NBLK + VBLK);    // fill sweeps (4 edges/thread) | gb | E-gemm
    dim3 g_prep(NBLK);
    dim3 g_agg(N_NODES / 8);                      // 12500 exact (8 nodes/block, 2/wave)
    dim3 g_po((N_GRAPHS * 64 + 255) / 256);       // 512

    hipMemsetAsync(cnt, 0, (size_t)N_NODES * sizeof(int), stream);

    // ---- single scattered pass, XCD-aligned range sweeps ----
    k_fill_slots<<<g_fill, blk, 0, stream>>>(row, col, cnt, slots, batch, start, emb, W1, E);

    // ---- dx = {dinv, x} hot table ----
    k_prep<<<g_prep, blk, 0, stream>>>(x, cnt, dx);

    // ---- layer-1 aggregate (fp32 FMA reconstruct) + layer-2 GEMM (tn2 -> fp16) ----
    k_agg_gemm<<<g_agg, blk, 0, stream>>>(dx, (const float4*)E, cnt, slots, b1, W2, Bt);

    // ---- layer-2 aggregate (fp16 pk-add, round-3 gather2) -> h2 fp32 (A) ----
    k_agg<<<g_agg, blk, 0, stream>>>((const uint4*)Bt, cnt, slots, b2, A);

    // ---- fused pool + classify ----
    k_pool_out<<<g_po, blk, 0, stream>>>(A, start, Wl, bl, out);
}

// Round 7
// 283.386 us; speedup vs baseline: 1.1696x; 1.0221x over previous
//
#include <hip/hip_runtime.h>
#include <hip/hip_fp16.h>

#define N_NODES  100000
#define N_EDGES  1600000
#define N_GRAPHS 2048
#define VOCAB    1000
#define EMBED    64
#define HID      64
#define N_CL     2
#define CAP      64     // max degree capacity (deg~Poisson(16); P(>=64)~3e-22/node)
#define NBLK     391    // ceil(N_NODES/256)
#define EBLK4    1563   // ceil(N_EDGES/4/256): 4 edges per thread
#define NQUAD    400000 // N_EDGES/4
#define VBLK     63     // ceil(VOCAB*16/256): E-gemm blocks
#define NSWEEP   8
#define RANGE    12500  // N_NODES / NSWEEP

typedef __half2 h2;
typedef int i4 __attribute__((ext_vector_type(4)));   // clang ext_vector: valid for nontemporal builtins

// pack float4 -> 4 fp16 (8B)
__device__ inline uint2 pack_h4(float4 a) {
    h2 lo = __float22half2_rn(make_float2(a.x, a.y));
    h2 hi = __float22half2_rn(make_float2(a.z, a.w));
    uint2 r;
    r.x = *reinterpret_cast<unsigned*>(&lo);
    r.y = *reinterpret_cast<unsigned*>(&hi);
    return r;
}

// packed fp16 accumulate: 4x v_pk_add_f16 per 16B row
__device__ inline void acc_h8(h2 acc[4], uint4 raw) {
    acc[0] = __hadd2(acc[0], *reinterpret_cast<h2*>(&raw.x));
    acc[1] = __hadd2(acc[1], *reinterpret_cast<h2*>(&raw.y));
    acc[2] = __hadd2(acc[2], *reinterpret_cast<h2*>(&raw.z));
    acc[3] = __hadd2(acc[3], *reinterpret_cast<h2*>(&raw.w));
}

// convert 4x half2 -> 2x float4
__device__ inline void h8_to_f(const h2 acc[4], float4& A, float4& B) {
    float2 f0 = __half22float2(acc[0]);
    float2 f1 = __half22float2(acc[1]);
    float2 f2 = __half22float2(acc[2]);
    float2 f3 = __half22float2(acc[3]);
    A.x = f0.x; A.y = f0.y; A.z = f1.x; A.w = f1.y;
    B.x = f2.x; B.y = f2.y; B.z = f3.x; B.w = f3.y;
}

__device__ inline void xor_reduce8(float4& A, float4& B) {
#pragma unroll
    for (int m = 8; m <= 32; m <<= 1) {
        A.x += __shfl_xor(A.x, m, 64); A.y += __shfl_xor(A.y, m, 64);
        A.z += __shfl_xor(A.z, m, 64); A.w += __shfl_xor(A.w, m, 64);
        B.x += __shfl_xor(B.x, m, 64); B.y += __shfl_xor(B.y, m, 64);
        B.z += __shfl_xor(B.z, m, 64); B.w += __shfl_xor(B.w, m, 64);
    }
}

// Transposed-slot gather: slotsT[pos][v] (pos-major). A block's 8 consecutive nodes share each
// [pos][v..] 128B line (L1-served); es lane owns pos es*4..es*4+3 (+32 in rare phase).
// Up to 8 outstanding 128B tn gathers per lane (v0/v1 interleaved).
__device__ inline void gather2T(const uint4* __restrict__ tn, const int* __restrict__ slotsT,
                                int v0, int v1, int n0, int n1, int es, int fg,
                                h2 a0[4], h2 a1[4]) {
    int base = es * 4;
    const int* s0p = slotsT + base * N_NODES + v0;
    const int* s1p = slotsT + base * N_NODES + v1;
    int q0[4], q1[4];
#pragma unroll
    for (int k = 0; k < 4; ++k) { q0[k] = s0p[k * N_NODES]; q1[k] = s1p[k * N_NODES]; }
#pragma unroll
    for (int k = 0; k < 4; ++k) {
        if (base + k < n0) acc_h8(a0, tn[q0[k] * 8 + fg]);
        if (base + k < n1) acc_h8(a1, tn[q1[k] * 8 + fg]);
    }
    if (n0 > 32 || n1 > 32) {               // rare phase (deg ~Poisson(16))
        int b2 = 32 + base;
        const int* t0p = slotsT + b2 * N_NODES + v0;
        const int* t1p = slotsT + b2 * N_NODES + v1;
        int p0[4], p1[4];
#pragma unroll
        for (int k = 0; k < 4; ++k) { p0[k] = t0p[k * N_NODES]; p1[k] = t1p[k * N_NODES]; }
#pragma unroll
        for (int k = 0; k < 4; ++k) {
            if (b2 + k < n0) acc_h8(a0, tn[p0[k] * 8 + fg]);
            if (b2 + k < n1) acc_h8(a1, tn[p1[k] * 8 + fg]);
        }
    }
}

// ================= bucket fill: XCD-aligned target-range sweeps + gb + E=emb@W1 ==================
// TRANSPOSED slot stores — slotsT[pos][c] instead of slots[c][pos]. Per-sweep hot write region
// shrinks 3.2MB -> ~2MB with densely-dirtied lines (32 nodes/line), attacking the 4-5x write
// amplification (WRITE_SIZE 65MB vs ~14MB dirty) and keeping cnt lines L2-resident.
__global__ __launch_bounds__(256) void k_fill_slots(const int* __restrict__ row, const int* __restrict__ col,
                                                    int* __restrict__ cnt, int* __restrict__ slotsT,
                                                    const int* __restrict__ batch, int* __restrict__ start,
                                                    const float* __restrict__ emb, const float* __restrict__ W1,
                                                    float* __restrict__ E) {
    int bid = blockIdx.x;
    if (bid < NSWEEP * EBLK4) {     // ---- fill sweep (XCD-interleaved, 4 edges/thread) ----
        int sweep = bid & (NSWEEP - 1);
        int t = (bid >> 3) * 256 + threadIdx.x;          // quad index
        if (t >= NQUAD) return;
        i4 c4 = __builtin_nontemporal_load((const i4*)col + t);
        unsigned lo = (unsigned)(sweep * RANGE);
        bool m0 = (unsigned)(c4.x - lo) < (unsigned)RANGE;
        bool m1 = (unsigned)(c4.y - lo) < (unsigned)RANGE;
        bool m2 = (unsigned)(c4.z - lo) < (unsigned)RANGE;
        bool m3 = (unsigned)(c4.w - lo) < (unsigned)RANGE;
        if (m0 | m1 | m2 | m3) {
            i4 r4 = __builtin_nontemporal_load((const i4*)row + t);
            if (m0) { int pos = atomicAdd(&cnt[c4.x], 1); if (pos < CAP) slotsT[pos * N_NODES + c4.x] = r4.x; }
            if (m1) { int pos = atomicAdd(&cnt[c4.y], 1); if (pos < CAP) slotsT[pos * N_NODES + c4.y] = r4.y; }
            if (m2) { int pos = atomicAdd(&cnt[c4.z], 1); if (pos < CAP) slotsT[pos * N_NODES + c4.z] = r4.z; }
            if (m3) { int pos = atomicAdd(&cnt[c4.w], 1); if (pos < CAP) slotsT[pos * N_NODES + c4.w] = r4.w; }
        }
    } else if (bid < NSWEEP * EBLK4 + NBLK) {  // ---- graph boundaries from sorted batch ----
        int v = (bid - NSWEEP * EBLK4) * 256 + threadIdx.x;
        if (v >= N_NODES) return;
        int b = batch[v];
        int pb = (v == 0) ? -1 : batch[v - 1];
        for (int g = pb + 1; g <= b; ++g) start[g] = v;
        if (v == N_NODES - 1)
            for (int g = b + 1; g <= N_GRAPHS; ++g) start[g] = N_NODES;
    } else {                        // ---- E[j] = emb[j] @ W1 (1000x64, float4/thread) ----
        int t = (bid - NSWEEP * EBLK4 - NBLK) * 256 + threadIdx.x;
        int j = t >> 4;
        int f4 = t & 15;
        if (j >= VOCAB) return;
        const float4* W4 = (const float4*)W1;
        const float* er = emb + j * EMBED;
        float4 acc = make_float4(0.f, 0.f, 0.f, 0.f);
#pragma unroll 8
        for (int k = 0; k < EMBED; ++k) {
            float hv = er[k];
            float4 w = W4[k * 16 + f4];
            acc.x += hv * w.x; acc.y += hv * w.y; acc.z += hv * w.z; acc.w += hv * w.w;
        }
        ((float4*)E)[t] = acc;
    }
}

// ================= tn1[v] = fp16( rsqrt(cnt[v]+1) * E[x[v]] ) =================
__global__ __launch_bounds__(256) void k_tn1(const int* __restrict__ x, const int* __restrict__ cnt,
                                             const float* __restrict__ E, uint2* __restrict__ tn) {
    int t = blockIdx.x * 256 + threadIdx.x;      // exact: N_NODES*16
    int v = t >> 4;
    int f4 = t & 15;
    float d = rsqrtf((float)(cnt[v] + 1));
    float4 a = ((const float4*)E)[x[v] * 16 + f4];
    a.x *= d; a.y *= d; a.z *= d; a.w *= d;
    tn[t] = pack_h4(a);
}

// ================= fused: layer-1 aggregate (fp16 pk-add) + finalize + layer-2 GEMM ==============
// 2 nodes/wave; lane = (es[0..7], fg[0..7]); transposed-slot gather (round-3-proven gather core)
__global__ __launch_bounds__(256) void k_agg_gemm(const uint4* __restrict__ tn,
                                                  const int* __restrict__ cnt,
                                                  const int* __restrict__ slotsT,
                                                  const float* __restrict__ bias,
                                                  const float* __restrict__ W2,
                                                  __half* __restrict__ tn2) {
    __shared__ float hrow[8][HID];
    int wid = threadIdx.x >> 6;
    int lane = threadIdx.x & 63;
    int fg = lane & 7;
    int es = lane >> 3;
    int v0 = blockIdx.x * 8 + wid * 2;
    int v1 = v0 + 1;
    int c0 = cnt[v0], c1 = cnt[v1];
    int n0 = min(c0, CAP), n1 = min(c1, CAP);
    h2 z = __float2half2_rn(0.f);
    h2 a0[4] = {z, z, z, z};
    h2 a1[4] = {z, z, z, z};
    if (es == 0) acc_h8(a0, tn[v0 * 8 + fg]);   // self loop v0
    if (es == 1) acc_h8(a1, tn[v1 * 8 + fg]);   // self loop v1
    gather2T(tn, slotsT, v0, v1, n0, n1, es, fg, a0, a1);
    float4 a0A, a0B, a1A, a1B;
    h8_to_f(a0, a0A, a0B);
    h8_to_f(a1, a1A, a1B);
    xor_reduce8(a0A, a0B);
    xor_reduce8(a1A, a1B);
    float d0 = rsqrtf((float)(c0 + 1));
    float d1 = rsqrtf((float)(c1 + 1));
    float4 bA = ((const float4*)bias)[fg * 2 + 0];
    float4 bB = ((const float4*)bias)[fg * 2 + 1];
    if (es == 0) {
        float4 oA, oB;
        oA.x = fmaxf(d0 * a0A.x + bA.x, 0.f); oA.y = fmaxf(d0 * a0A.y + bA.y, 0.f);
        oA.z = fmaxf(d0 * a0A.z + bA.z, 0.f); oA.w = fmaxf(d0 * a0A.w + bA.w, 0.f);
        oB.x = fmaxf(d0 * a0B.x + bB.x, 0.f); oB.y = fmaxf(d0 * a0B.y + bB.y, 0.f);
        oB.z = fmaxf(d0 * a0B.z + bB.z, 0.f); oB.w = fmaxf(d0 * a0B.w + bB.w, 0.f);
        ((float4*)&hrow[wid * 2][fg * 8])[0] = oA;
        ((float4*)&hrow[wid * 2][fg * 8])[1] = oB;
    }
    if (es == 1) {
        float4 oA, oB;
        oA.x = fmaxf(d1 * a1A.x + bA.x, 0.f); oA.y = fmaxf(d1 * a1A.y + bA.y, 0.f);
        oA.z = fmaxf(d1 * a1A.z + bA.z, 0.f); oA.w = fmaxf(d1 * a1A.w + bA.w, 0.f);
        oB.x = fmaxf(d1 * a1B.x + bB.x, 0.f); oB.y = fmaxf(d1 * a1B.y + bB.y, 0.f);
        oB.z = fmaxf(d1 * a1B.z + bB.z, 0.f); oB.w = fmaxf(d1 * a1B.w + bB.w, 0.f);
        ((float4*)&hrow[wid * 2 + 1][fg * 8])[0] = oA;
        ((float4*)&hrow[wid * 2 + 1][fg * 8])[1] = oB;
    }
    __syncthreads();
    // ---- layer-2 GEMM: lane computes feature `lane` for both nodes (float4 LDS broadcast reads) ----
    const float4* h04 = (const float4*)hrow[wid * 2];
    const float4* h14 = (const float4*)hrow[wid * 2 + 1];
    float s0 = 0.f, s1 = 0.f;
#pragma unroll 4
    for (int k4 = 0; k4 < 16; ++k4) {
        float4 ha = h04[k4];
        float4 hb = h14[k4];
        int k = k4 * 4;
        float w0 = W2[(k + 0) * HID + lane];
        float w1 = W2[(k + 1) * HID + lane];
        float w2 = W2[(k + 2) * HID + lane];
        float w3 = W2[(k + 3) * HID + lane];
        s0 += ha.x * w0 + ha.y * w1 + ha.z * w2 + ha.w * w3;
        s1 += hb.x * w0 + hb.y * w1 + hb.z * w2 + hb.w * w3;
    }
    tn2[v0 * HID + lane] = __float2half(d0 * s0);
    tn2[v1 * HID + lane] = __float2half(d1 * s1);
}

// ---------------- layer-2 aggregate (fp16 pk-add, transposed-slot gather) -> fp32 ----------------
__global__ __launch_bounds__(256) void k_agg(const uint4* __restrict__ tn,
                                             const int* __restrict__ cnt,
                                             const int* __restrict__ slotsT,
                                             const float* __restrict__ bias,
                                             float* __restrict__ h) {
    int wid = threadIdx.x >> 6;
    int lane = threadIdx.x & 63;
    int fg = lane & 7;
    int es = lane >> 3;
    int v0 = blockIdx.x * 8 + wid * 2;
    int v1 = v0 + 1;
    int c0 = cnt[v0], c1 = cnt[v1];
    int n0 = min(c0, CAP), n1 = min(c1, CAP);
    h2 z = __float2half2_rn(0.f);
    h2 a0[4] = {z, z, z, z};
    h2 a1[4] = {z, z, z, z};
    if (es == 0) acc_h8(a0, tn[v0 * 8 + fg]);
    if (es == 1) acc_h8(a1, tn[v1 * 8 + fg]);
    gather2T(tn, slotsT, v0, v1, n0, n1, es, fg, a0, a1);
    float4 a0A, a0B, a1A, a1B;
    h8_to_f(a0, a0A, a0B);
    h8_to_f(a1, a1A, a1B);
    xor_reduce8(a0A, a0B);
    xor_reduce8(a1A, a1B);
    float4 bA = ((const float4*)bias)[fg * 2 + 0];
    float4 bB = ((const float4*)bias)[fg * 2 + 1];
    if (es == 0) {
        float d0 = rsqrtf((float)(c0 + 1));
        float4 oA, oB;
        oA.x = fmaxf(d0 * a0A.x + bA.x, 0.f); oA.y = fmaxf(d0 * a0A.y + bA.y, 0.f);
        oA.z = fmaxf(d0 * a0A.z + bA.z, 0.f); oA.w = fmaxf(d0 * a0A.w + bA.w, 0.f);
        oB.x = fmaxf(d0 * a0B.x + bB.x, 0.f); oB.y = fmaxf(d0 * a0B.y + bB.y, 0.f);
        oB.z = fmaxf(d0 * a0B.z + bB.z, 0.f); oB.w = fmaxf(d0 * a0B.w + bB.w, 0.f);
        ((float4*)&h[v0 * HID + fg * 8])[0] = oA;
        ((float4*)&h[v0 * HID + fg * 8])[1] = oB;
    }
    if (es == 1) {
        float d1 = rsqrtf((float)(c1 + 1));
        float4 oA, oB;
        oA.x = fmaxf(d1 * a1A.x + bA.x, 0.f); oA.y = fmaxf(d1 * a1A.y + bA.y, 0.f);
        oA.z = fmaxf(d1 * a1A.z + bA.z, 0.f); oA.w = fmaxf(d1 * a1A.w + bA.w, 0.f);
        oB.x = fmaxf(d1 * a1B.x + bB.x, 0.f); oB.y = fmaxf(d1 * a1B.y + bB.y, 0.f);
        oB.z = fmaxf(d1 * a1B.z + bB.z, 0.f); oB.w = fmaxf(d1 * a1B.w + bB.w, 0.f);
        ((float4*)&h[v1 * HID + fg * 8])[0] = oA;
        ((float4*)&h[v1 * HID + fg * 8])[1] = oB;
    }
}

// ---------------- fused mean-pool + projection ----------------
__global__ __launch_bounds__(256) void k_pool_out(const float* __restrict__ h,
                                                  const int* __restrict__ start,
                                                  const float* __restrict__ Wl,
                                                  const float* __restrict__ bl,
                                                  float* __restrict__ out) {
    int g = (blockIdx.x * 256 + threadIdx.x) >> 6;
    int f = threadIdx.x & 63;
    if (g >= N_GRAPHS) return;
    int s = start[g], e = start[g + 1];
    float acc = 0.f;
    int v = s;
    for (; v + 4 <= e; v += 4) {
        float a0 = h[(v + 0) * HID + f];
        float a1 = h[(v + 1) * HID + f];
        float a2 = h[(v + 2) * HID + f];
        float a3 = h[(v + 3) * HID + f];
        acc += (a0 + a1) + (a2 + a3);
    }
    for (; v < e; ++v) acc += h[v * HID + f];
    float m = acc / fmaxf((float)(e - s), 1.f);
    float p0 = m * Wl[f * N_CL + 0];
    float p1 = m * Wl[f * N_CL + 1];
#pragma unroll
    for (int off = 32; off > 0; off >>= 1) {
        p0 += __shfl_down(p0, off, 64);
        p1 += __shfl_down(p1, off, 64);
    }
    if (f == 0) {
        out[g * N_CL + 0] = p0 + bl[0];
        out[g * N_CL + 1] = p1 + bl[1];
    }
}

extern "C" void kernel_launch(void* const* d_in, const int* in_sizes, int n_in,
                              void* d_out, int out_size, void* d_ws, size_t ws_size,
                              hipStream_t stream) {
    const int*   x     = (const int*)d_in[0];
    const int*   ei    = (const int*)d_in[1];        // [2, E] flat: sources then targets
    const int*   batch = (const int*)d_in[2];
    const float* emb   = (const float*)d_in[3];
    const float* W1    = (const float*)d_in[4];
    const float* b1    = (const float*)d_in[5];
    const float* W2    = (const float*)d_in[6];
    const float* b2    = (const float*)d_in[7];
    const float* Wl    = (const float*)d_in[8];
    const float* bl    = (const float*)d_in[9];
    float* out = (float*)d_out;

    const int* row = ei;             // sources
    const int* col = ei + N_EDGES;   // targets

    // ---- workspace layout (~65 MB) ----
    char* ws = (char*)d_ws;
    size_t off = 0;
    auto alloc = [&](size_t bytes) { char* p = ws + off; off = (off + bytes + 511) & ~(size_t)511; return p; };
    const size_t FEAT_BYTES  = (size_t)N_NODES * HID * sizeof(float);      // 25.6 MB
    const size_t FEATH_BYTES = (size_t)N_NODES * HID * sizeof(__half);     // 12.8 MB
    float* A      = (float*)alloc(FEAT_BYTES);             // tn1 (fp16, low half), later h2 (fp32)
    __half* Bt    = (__half*)alloc(FEATH_BYTES);           // tn2 fp16
    int*   slotsT = (int*)  alloc((size_t)N_NODES * CAP * sizeof(int));    // 25.6 MB (pos-major)
    float* E      = (float*)alloc((size_t)VOCAB * HID * sizeof(float));    // 256 KB
    int*   start  = (int*)  alloc((size_t)(N_GRAPHS + 1) * sizeof(int));
    int*   cnt    = (int*)  alloc((size_t)N_NODES * sizeof(int));          // zeroed

    dim3 blk(256);
    dim3 g_fill(NSWEEP * EBLK4 + NBLK + VBLK);    // fill sweeps (4 edges/thread) | gb | E-gemm
    dim3 g_tn1(N_NODES * 16 / 256);               // 6250 exact
    dim3 g_agg(N_NODES / 8);                      // 12500 exact (8 nodes/block, 2/wave)
    dim3 g_po((N_GRAPHS * 64 + 255) / 256);       // 512

    hipMemsetAsync(cnt, 0, (size_t)N_NODES * sizeof(int), stream);

    // ---- single scattered pass, XCD-aligned range sweeps, transposed slot stores ----
    k_fill_slots<<<g_fill, blk, 0, stream>>>(row, col, cnt, slotsT, batch, start, emb, W1, E);

    // ---- tn1 = fp16(dinv * E[x]) ----
    k_tn1<<<g_tn1, blk, 0, stream>>>(x, cnt, E, (uint2*)A);

    // ---- layer-1 aggregate (fp16 pk-add, transposed gather) + layer-2 GEMM (tn2 -> fp16) ----
    k_agg_gemm<<<g_agg, blk, 0, stream>>>((const uint4*)A, cnt, slotsT, b1, W2, Bt);

    // ---- layer-2 aggregate (fp16 pk-add, transposed gather) -> h2 fp32 (A reused) ----
    k_agg<<<g_agg, blk, 0, stream>>>((const uint4*)Bt, cnt, slotsT, b2, A);

    // ---- fused pool + classify ----
    k_pool_out<<<g_po, blk, 0, stream>>>(A, start, Wl, bl, out);
}

// Round 8
// 277.431 us; speedup vs baseline: 1.1947x; 1.0215x over previous
//
#include <hip/hip_runtime.h>
#include <hip/hip_fp16.h>

#define N_NODES  100000
#define N_EDGES  1600000
#define N_GRAPHS 2048
#define VOCAB    1000
#define EMBED    64
#define HID      64
#define N_CL     2
#define CAP      64     // max degree capacity (deg~Poisson(16); P(>=64)~3e-22/node)
#define NBLK     391    // ceil(N_NODES/256)
#define EBLK4    1563   // ceil(N_EDGES/4/256): 4 edges per thread
#define NQUAD    400000 // N_EDGES/4
#define VBLK     63     // ceil(VOCAB*16/256): E-gemm blocks
#define NSWEEP   8
#define RANGE    12500  // N_NODES / NSWEEP

typedef __half2 h2;
typedef int i4 __attribute__((ext_vector_type(4)));   // clang ext_vector: valid for nontemporal builtins

// pack float4 -> 4 fp16 (8B)
__device__ inline uint2 pack_h4(float4 a) {
    h2 lo = __float22half2_rn(make_float2(a.x, a.y));
    h2 hi = __float22half2_rn(make_float2(a.z, a.w));
    uint2 r;
    r.x = *reinterpret_cast<unsigned*>(&lo);
    r.y = *reinterpret_cast<unsigned*>(&hi);
    return r;
}

// packed fp16 accumulate: 4x v_pk_add_f16 per 16B row
__device__ inline void acc_h8(h2 acc[4], uint4 raw) {
    acc[0] = __hadd2(acc[0], *reinterpret_cast<h2*>(&raw.x));
    acc[1] = __hadd2(acc[1], *reinterpret_cast<h2*>(&raw.y));
    acc[2] = __hadd2(acc[2], *reinterpret_cast<h2*>(&raw.z));
    acc[3] = __hadd2(acc[3], *reinterpret_cast<h2*>(&raw.w));
}

// convert 4x half2 -> 2x float4
__device__ inline void h8_to_f(const h2 acc[4], float4& A, float4& B) {
    float2 f0 = __half22float2(acc[0]);
    float2 f1 = __half22float2(acc[1]);
    float2 f2 = __half22float2(acc[2]);
    float2 f3 = __half22float2(acc[3]);
    A.x = f0.x; A.y = f0.y; A.z = f1.x; A.w = f1.y;
    B.x = f2.x; B.y = f2.y; B.z = f3.x; B.w = f3.y;
}

__device__ inline void xor_reduce8(float4& A, float4& B) {
#pragma unroll
    for (int m = 8; m <= 32; m <<= 1) {
        A.x += __shfl_xor(A.x, m, 64); A.y += __shfl_xor(A.y, m, 64);
        A.z += __shfl_xor(A.z, m, 64); A.w += __shfl_xor(A.w, m, 64);
        B.x += __shfl_xor(B.x, m, 64); B.y += __shfl_xor(B.y, m, 64);
        B.z += __shfl_xor(B.z, m, 64); B.w += __shfl_xor(B.w, m, 64);
    }
}

// MLP-maximized gather (round-3-proven): int4 slot-index loads, v0/v1 interleaved,
// up to 8 outstanding 128B gathers per lane.
__device__ inline void gather2(const uint4* __restrict__ tn,
                               const int* __restrict__ sl0, const int* __restrict__ sl1,
                               int n0, int n1, int es, int fg, h2 a0[4], h2 a1[4]) {
    int base = es * 4;
    int4 q0 = ((const int4*)sl0)[es];       // slots base..base+3 of v0 (safe: full CAP allocated)
    int4 q1 = ((const int4*)sl1)[es];
    if (base + 0 < n0) acc_h8(a0, tn[q0.x * 8 + fg]);
    if (base + 0 < n1) acc_h8(a1, tn[q1.x * 8 + fg]);
    if (base + 1 < n0) acc_h8(a0, tn[q0.y * 8 + fg]);
    if (base + 1 < n1) acc_h8(a1, tn[q1.y * 8 + fg]);
    if (base + 2 < n0) acc_h8(a0, tn[q0.z * 8 + fg]);
    if (base + 2 < n1) acc_h8(a1, tn[q1.z * 8 + fg]);
    if (base + 3 < n0) acc_h8(a0, tn[q0.w * 8 + fg]);
    if (base + 3 < n1) acc_h8(a1, tn[q1.w * 8 + fg]);
    if (n0 > 32 || n1 > 32) {               // rare phase (deg ~Poisson(16))
        int b2 = 32 + es * 4;
        int4 p0 = ((const int4*)sl0)[8 + es];
        int4 p1 = ((const int4*)sl1)[8 + es];
        if (b2 + 0 < n0) acc_h8(a0, tn[p0.x * 8 + fg]);
        if (b2 + 0 < n1) acc_h8(a1, tn[p1.x * 8 + fg]);
        if (b2 + 1 < n0) acc_h8(a0, tn[p0.y * 8 + fg]);
        if (b2 + 1 < n1) acc_h8(a1, tn[p1.y * 8 + fg]);
        if (b2 + 2 < n0) acc_h8(a0, tn[p0.z * 8 + fg]);
        if (b2 + 2 < n1) acc_h8(a1, tn[p1.z * 8 + fg]);
        if (b2 + 3 < n0) acc_h8(a0, tn[p0.w * 8 + fg]);
        if (b2 + 3 < n1) acc_h8(a1, tn[p1.w * 8 + fg]);
    }
}

// ================= bucket fill: XCD-aligned target-range sweeps + gb + E=emb@W1 ==================
// This round: DECOUPLED col/row loads — both nt loads issue back-to-back unconditionally (row addr
// is a pure function of t), collapsing the former col->branch->row 2-level memory chain into one
// latency level. Fill pinned at 77us across 4 variants that all kept row dependent on col.
__global__ __launch_bounds__(256) void k_fill_slots(const int* __restrict__ row, const int* __restrict__ col,
                                                    int* __restrict__ cnt, int* __restrict__ slots,
                                                    const int* __restrict__ batch, int* __restrict__ start,
                                                    const float* __restrict__ emb, const float* __restrict__ W1,
                                                    float* __restrict__ E) {
    int bid = blockIdx.x;
    if (bid < NSWEEP * EBLK4) {     // ---- fill sweep (XCD-interleaved, 4 edges/thread) ----
        int sweep = bid & (NSWEEP - 1);
        int t = (bid >> 3) * 256 + threadIdx.x;          // quad index
        if (t >= NQUAD) return;
        i4 c4 = __builtin_nontemporal_load((const i4*)col + t);
        i4 r4 = __builtin_nontemporal_load((const i4*)row + t);   // independent, issued together
        unsigned lo = (unsigned)(sweep * RANGE);
        if ((unsigned)(c4.x - lo) < (unsigned)RANGE) { int pos = atomicAdd(&cnt[c4.x], 1); if (pos < CAP) slots[c4.x * CAP + pos] = r4.x; }
        if ((unsigned)(c4.y - lo) < (unsigned)RANGE) { int pos = atomicAdd(&cnt[c4.y], 1); if (pos < CAP) slots[c4.y * CAP + pos] = r4.y; }
        if ((unsigned)(c4.z - lo) < (unsigned)RANGE) { int pos = atomicAdd(&cnt[c4.z], 1); if (pos < CAP) slots[c4.z * CAP + pos] = r4.z; }
        if ((unsigned)(c4.w - lo) < (unsigned)RANGE) { int pos = atomicAdd(&cnt[c4.w], 1); if (pos < CAP) slots[c4.w * CAP + pos] = r4.w; }
    } else if (bid < NSWEEP * EBLK4 + NBLK) {  // ---- graph boundaries from sorted batch ----
        int v = (bid - NSWEEP * EBLK4) * 256 + threadIdx.x;
        if (v >= N_NODES) return;
        int b = batch[v];
        int pb = (v == 0) ? -1 : batch[v - 1];
        for (int g = pb + 1; g <= b; ++g) start[g] = v;
        if (v == N_NODES - 1)
            for (int g = b + 1; g <= N_GRAPHS; ++g) start[g] = N_NODES;
    } else {                        // ---- E[j] = emb[j] @ W1 (1000x64, float4/thread) ----
        int t = (bid - NSWEEP * EBLK4 - NBLK) * 256 + threadIdx.x;
        int j = t >> 4;
        int f4 = t & 15;
        if (j >= VOCAB) return;
        const float4* W4 = (const float4*)W1;
        const float* er = emb + j * EMBED;
        float4 acc = make_float4(0.f, 0.f, 0.f, 0.f);
#pragma unroll 8
        for (int k = 0; k < EMBED; ++k) {
            float hv = er[k];
            float4 w = W4[k * 16 + f4];
            acc.x += hv * w.x; acc.y += hv * w.y; acc.z += hv * w.z; acc.w += hv * w.w;
        }
        ((float4*)E)[t] = acc;
    }
}

// ================= tn1[v] = fp16( rsqrt(cnt[v]+1) * E[x[v]] ) =================
__global__ __launch_bounds__(256) void k_tn1(const int* __restrict__ x, const int* __restrict__ cnt,
                                             const float* __restrict__ E, uint2* __restrict__ tn) {
    int t = blockIdx.x * 256 + threadIdx.x;      // exact: N_NODES*16
    int v = t >> 4;
    int f4 = t & 15;
    float d = rsqrtf((float)(cnt[v] + 1));
    float4 a = ((const float4*)E)[x[v] * 16 + f4];
    a.x *= d; a.y *= d; a.z *= d; a.w *= d;
    tn[t] = pack_h4(a);
}

// ================= fused: layer-1 aggregate (fp16 pk-add) + finalize + layer-2 GEMM ==============
// 2 nodes/wave; lane = (es[0..7], fg[0..7]); packed-fp16 per-lane partials, fp32 reduce
__global__ __launch_bounds__(256) void k_agg_gemm(const uint4* __restrict__ tn,
                                                  const int* __restrict__ cnt,
                                                  const int* __restrict__ slots,
                                                  const float* __restrict__ bias,
                                                  const float* __restrict__ W2,
                                                  __half* __restrict__ tn2) {
    __shared__ float hrow[8][HID];
    int wid = threadIdx.x >> 6;
    int lane = threadIdx.x & 63;
    int fg = lane & 7;
    int es = lane >> 3;
    int v0 = blockIdx.x * 8 + wid * 2;
    int v1 = v0 + 1;
    int c0 = cnt[v0], c1 = cnt[v1];
    int n0 = min(c0, CAP), n1 = min(c1, CAP);
    h2 z = __float2half2_rn(0.f);
    h2 a0[4] = {z, z, z, z};
    h2 a1[4] = {z, z, z, z};
    if (es == 0) acc_h8(a0, tn[v0 * 8 + fg]);   // self loop v0
    if (es == 1) acc_h8(a1, tn[v1 * 8 + fg]);   // self loop v1
    gather2(tn, slots + v0 * CAP, slots + v1 * CAP, n0, n1, es, fg, a0, a1);
    float4 a0A, a0B, a1A, a1B;
    h8_to_f(a0, a0A, a0B);
    h8_to_f(a1, a1A, a1B);
    xor_reduce8(a0A, a0B);
    xor_reduce8(a1A, a1B);
    float d0 = rsqrtf((float)(c0 + 1));
    float d1 = rsqrtf((float)(c1 + 1));
    float4 bA = ((const float4*)bias)[fg * 2 + 0];
    float4 bB = ((const float4*)bias)[fg * 2 + 1];
    if (es == 0) {
        float4 oA, oB;
        oA.x = fmaxf(d0 * a0A.x + bA.x, 0.f); oA.y = fmaxf(d0 * a0A.y + bA.y, 0.f);
        oA.z = fmaxf(d0 * a0A.z + bA.z, 0.f); oA.w = fmaxf(d0 * a0A.w + bA.w, 0.f);
        oB.x = fmaxf(d0 * a0B.x + bB.x, 0.f); oB.y = fmaxf(d0 * a0B.y + bB.y, 0.f);
        oB.z = fmaxf(d0 * a0B.z + bB.z, 0.f); oB.w = fmaxf(d0 * a0B.w + bB.w, 0.f);
        ((float4*)&hrow[wid * 2][fg * 8])[0] = oA;
        ((float4*)&hrow[wid * 2][fg * 8])[1] = oB;
    }
    if (es == 1) {
        float4 oA, oB;
        oA.x = fmaxf(d1 * a1A.x + bA.x, 0.f); oA.y = fmaxf(d1 * a1A.y + bA.y, 0.f);
        oA.z = fmaxf(d1 * a1A.z + bA.z, 0.f); oA.w = fmaxf(d1 * a1A.w + bA.w, 0.f);
        oB.x = fmaxf(d1 * a1B.x + bB.x, 0.f); oB.y = fmaxf(d1 * a1B.y + bB.y, 0.f);
        oB.z = fmaxf(d1 * a1B.z + bB.z, 0.f); oB.w = fmaxf(d1 * a1B.w + bB.w, 0.f);
        ((float4*)&hrow[wid * 2 + 1][fg * 8])[0] = oA;
        ((float4*)&hrow[wid * 2 + 1][fg * 8])[1] = oB;
    }
    __syncthreads();
    // ---- layer-2 GEMM: lane computes feature `lane` for both nodes (float4 LDS broadcast reads) ----
    const float4* h04 = (const float4*)hrow[wid * 2];
    const float4* h14 = (const float4*)hrow[wid * 2 + 1];
    float s0 = 0.f, s1 = 0.f;
#pragma unroll 4
    for (int k4 = 0; k4 < 16; ++k4) {
        float4 ha = h04[k4];
        float4 hb = h14[k4];
        int k = k4 * 4;
        float w0 = W2[(k + 0) * HID + lane];
        float w1 = W2[(k + 1) * HID + lane];
        float w2 = W2[(k + 2) * HID + lane];
        float w3 = W2[(k + 3) * HID + lane];
        s0 += ha.x * w0 + ha.y * w1 + ha.z * w2 + ha.w * w3;
        s1 += hb.x * w0 + hb.y * w1 + hb.z * w2 + hb.w * w3;
    }
    tn2[v0 * HID + lane] = __float2half(d0 * s0);
    tn2[v1 * HID + lane] = __float2half(d1 * s1);
}

// ---------------- layer-2 aggregate (fp16 pk-add, gather2) — 2 nodes/wave -> fp32 ----------------
__global__ __launch_bounds__(256) void k_agg(const uint4* __restrict__ tn,
                                             const int* __restrict__ cnt,
                                             const int* __restrict__ slots,
                                             const float* __restrict__ bias,
                                             float* __restrict__ h) {
    int wid = threadIdx.x >> 6;
    int lane = threadIdx.x & 63;
    int fg = lane & 7;
    int es = lane >> 3;
    int v0 = blockIdx.x * 8 + wid * 2;
    int v1 = v0 + 1;
    int c0 = cnt[v0], c1 = cnt[v1];
    int n0 = min(c0, CAP), n1 = min(c1, CAP);
    h2 z = __float2half2_rn(0.f);
    h2 a0[4] = {z, z, z, z};
    h2 a1[4] = {z, z, z, z};
    if (es == 0) acc_h8(a0, tn[v0 * 8 + fg]);
    if (es == 1) acc_h8(a1, tn[v1 * 8 + fg]);
    gather2(tn, slots + v0 * CAP, slots + v1 * CAP, n0, n1, es, fg, a0, a1);
    float4 a0A, a0B, a1A, a1B;
    h8_to_f(a0, a0A, a0B);
    h8_to_f(a1, a1A, a1B);
    xor_reduce8(a0A, a0B);
    xor_reduce8(a1A, a1B);
    float4 bA = ((const float4*)bias)[fg * 2 + 0];
    float4 bB = ((const float4*)bias)[fg * 2 + 1];
    if (es == 0) {
        float d0 = rsqrtf((float)(c0 + 1));
        float4 oA, oB;
        oA.x = fmaxf(d0 * a0A.x + bA.x, 0.f); oA.y = fmaxf(d0 * a0A.y + bA.y, 0.f);
        oA.z = fmaxf(d0 * a0A.z + bA.z, 0.f); oA.w = fmaxf(d0 * a0A.w + bA.w, 0.f);
        oB.x = fmaxf(d0 * a0B.x + bB.x, 0.f); oB.y = fmaxf(d0 * a0B.y + bB.y, 0.f);
        oB.z = fmaxf(d0 * a0B.z + bB.z, 0.f); oB.w = fmaxf(d0 * a0B.w + bB.w, 0.f);
        ((float4*)&h[v0 * HID + fg * 8])[0] = oA;
        ((float4*)&h[v0 * HID + fg * 8])[1] = oB;
    }
    if (es == 1) {
        float d1 = rsqrtf((float)(c1 + 1));
        float4 oA, oB;
        oA.x = fmaxf(d1 * a1A.x + bA.x, 0.f); oA.y = fmaxf(d1 * a1A.y + bA.y, 0.f);
        oA.z = fmaxf(d1 * a1A.z + bA.z, 0.f); oA.w = fmaxf(d1 * a1A.w + bA.w, 0.f);
        oB.x = fmaxf(d1 * a1B.x + bB.x, 0.f); oB.y = fmaxf(d1 * a1B.y + bB.y, 0.f);
        oB.z = fmaxf(d1 * a1B.z + bB.z, 0.f); oB.w = fmaxf(d1 * a1B.w + bB.w, 0.f);
        ((float4*)&h[v1 * HID + fg * 8])[0] = oA;
        ((float4*)&h[v1 * HID + fg * 8])[1] = oB;
    }
}

// ---------------- fused mean-pool + projection ----------------
__global__ __launch_bounds__(256) void k_pool_out(const float* __restrict__ h,
                                                  const int* __restrict__ start,
                                                  const float* __restrict__ Wl,
                                                  const float* __restrict__ bl,
                                                  float* __restrict__ out) {
    int g = (blockIdx.x * 256 + threadIdx.x) >> 6;
    int f = threadIdx.x & 63;
    if (g >= N_GRAPHS) return;
    int s = start[g], e = start[g + 1];
    float acc = 0.f;
    int v = s;
    for (; v + 4 <= e; v += 4) {
        float a0 = h[(v + 0) * HID + f];
        float a1 = h[(v + 1) * HID + f];
        float a2 = h[(v + 2) * HID + f];
        float a3 = h[(v + 3) * HID + f];
        acc += (a0 + a1) + (a2 + a3);
    }
    for (; v < e; ++v) acc += h[v * HID + f];
    float m = acc / fmaxf((float)(e - s), 1.f);
    float p0 = m * Wl[f * N_CL + 0];
    float p1 = m * Wl[f * N_CL + 1];
#pragma unroll
    for (int off = 32; off > 0; off >>= 1) {
        p0 += __shfl_down(p0, off, 64);
        p1 += __shfl_down(p1, off, 64);
    }
    if (f == 0) {
        out[g * N_CL + 0] = p0 + bl[0];
        out[g * N_CL + 1] = p1 + bl[1];
    }
}

extern "C" void kernel_launch(void* const* d_in, const int* in_sizes, int n_in,
                              void* d_out, int out_size, void* d_ws, size_t ws_size,
                              hipStream_t stream) {
    const int*   x     = (const int*)d_in[0];
    const int*   ei    = (const int*)d_in[1];        // [2, E] flat: sources then targets
    const int*   batch = (const int*)d_in[2];
    const float* emb   = (const float*)d_in[3];
    const float* W1    = (const float*)d_in[4];
    const float* b1    = (const float*)d_in[5];
    const float* W2    = (const float*)d_in[6];
    const float* b2    = (const float*)d_in[7];
    const float* Wl    = (const float*)d_in[8];
    const float* bl    = (const float*)d_in[9];
    float* out = (float*)d_out;

    const int* row = ei;             // sources
    const int* col = ei + N_EDGES;   // targets

    // ---- workspace layout (~65 MB) ----
    char* ws = (char*)d_ws;
    size_t off = 0;
    auto alloc = [&](size_t bytes) { char* p = ws + off; off = (off + bytes + 511) & ~(size_t)511; return p; };
    const size_t FEAT_BYTES  = (size_t)N_NODES * HID * sizeof(float);      // 25.6 MB
    const size_t FEATH_BYTES = (size_t)N_NODES * HID * sizeof(__half);     // 12.8 MB
    float* A      = (float*)alloc(FEAT_BYTES);             // tn1 (fp16, low half), later h2 (fp32)
    __half* Bt    = (__half*)alloc(FEATH_BYTES);           // tn2 fp16
    int*   slots  = (int*)  alloc((size_t)N_NODES * CAP * sizeof(int));    // 25.6 MB
    float* E      = (float*)alloc((size_t)VOCAB * HID * sizeof(float));    // 256 KB
    int*   start  = (int*)  alloc((size_t)(N_GRAPHS + 1) * sizeof(int));
    int*   cnt    = (int*)  alloc((size_t)N_NODES * sizeof(int));          // zeroed

    dim3 blk(256);
    dim3 g_fill(NSWEEP * EBLK4 + NBLK + VBLK);    // fill sweeps (4 edges/thread) | gb | E-gemm
    dim3 g_tn1(N_NODES * 16 / 256);               // 6250 exact
    dim3 g_agg(N_NODES / 8);                      // 12500 exact (8 nodes/block, 2/wave)
    dim3 g_po((N_GRAPHS * 64 + 255) / 256);       // 512

    hipMemsetAsync(cnt, 0, (size_t)N_NODES * sizeof(int), stream);

    // ---- single scattered pass, XCD-aligned range sweeps, decoupled col/row loads ----
    k_fill_slots<<<g_fill, blk, 0, stream>>>(row, col, cnt, slots, batch, start, emb, W1, E);

    // ---- tn1 = fp16(dinv * E[x]) ----
    k_tn1<<<g_tn1, blk, 0, stream>>>(x, cnt, E, (uint2*)A);

    // ---- layer-1 aggregate (fp16 pk-add, gather2) + layer-2 GEMM (tn2 -> fp16) ----
    k_agg_gemm<<<g_agg, blk, 0, stream>>>((const uint4*)A, cnt, slots, b1, W2, Bt);

    // ---- layer-2 aggregate (fp16 pk-add, gather2) -> h2 fp32 (A reused) ----
    k_agg<<<g_agg, blk, 0, stream>>>((const uint4*)Bt, cnt, slots, b2, A);

    // ---- fused pool + classify ----
    k_pool_out<<<g_po, blk, 0, stream>>>(A, start, Wl, bl, out);
}